// Round 3
// baseline (744.906 us; speedup 1.0000x reference)
//
#include <hip/hip_runtime.h>
#include <hip/hip_bf16.h>

#define B_ 32
#define S_ 1024
#define D_ 512
#define PSTR 1048    // P row stride in bf16 elems (524 dw; frag reads land at data-minimum phases)

typedef __attribute__((ext_vector_type(8))) short short8;
typedef __attribute__((ext_vector_type(4))) float f32x4;

__device__ __forceinline__ unsigned short f2bf(float f) {
    unsigned u = __float_as_uint(f);
    u += 0x7FFFu + ((u >> 16) & 1u);   // round-to-nearest-even
    return (unsigned short)(u >> 16);
}
__device__ __forceinline__ float bf2f(unsigned short s) {
    return __uint_as_float(((unsigned)s) << 16);
}

// ===================== prep: K -> KT bf16, fragment-native =====================
// KT[b][ds(16)][kcol(1024)][dquad(4)][8]; contiguous 16B writes per lane.
__global__ __launch_bounds__(256) void prep_k(const float* __restrict__ K,
                                              unsigned short* __restrict__ KT) {
    const int blk = blockIdx.x;          // B*16*16
    const int b  = blk >> 8;
    const int ds = (blk >> 4) & 15;
    const int sg = blk & 15;
    const int t  = threadIdx.x;
    const int dq = t & 3;
    const int s  = sg * 64 + (t >> 2);
    const float* src = K + ((size_t)(b * S_ + s)) * D_ + ds * 32 + dq * 8;
    const float4 a = *reinterpret_cast<const float4*>(src);
    const float4 c = *reinterpret_cast<const float4*>(src + 4);
    short8 p;
    p[0]=(short)f2bf(a.x); p[1]=(short)f2bf(a.y); p[2]=(short)f2bf(a.z); p[3]=(short)f2bf(a.w);
    p[4]=(short)f2bf(c.x); p[5]=(short)f2bf(c.y); p[6]=(short)f2bf(c.z); p[7]=(short)f2bf(c.w);
    unsigned short* dst = KT + (size_t)b * 524288 + (((ds * 1024 + s) * 4 + dq) * 8);
    *reinterpret_cast<short8*>(dst) = p;
}

// ===================== prep: V -> VT bf16, transposed fragment-native =====================
// VT[b][kk(32)][dcol(512)][kquad(4)][8]
__global__ __launch_bounds__(256) void prep_v(const float* __restrict__ V,
                                              unsigned short* __restrict__ VT) {
    __shared__ float st[32 * 260];
    const int blk = blockIdx.x;          // B*32*2
    const int b  = blk >> 6;
    const int kk = (blk >> 1) & 31;
    const int dh = blk & 1;
    const int t  = threadIdx.x;
    const int r0 = t >> 6;
    const int c4 = (t & 63) * 4;
    #pragma unroll
    for (int p = 0; p < 8; ++p) {
        const int s = r0 + p * 4;
        const float4 val = *reinterpret_cast<const float4*>(
            V + ((size_t)(b * S_ + kk * 32 + s)) * D_ + dh * 256 + c4);
        *reinterpret_cast<float4*>(&st[s * 260 + c4]) = val;
    }
    __syncthreads();
    const int dcol = t;
    unsigned short* dst = VT + (size_t)b * 524288 + ((kk * 512 + dh * 256 + dcol) * 4) * 8;
    #pragma unroll
    for (int kq = 0; kq < 4; ++kq) {
        short8 p;
        #pragma unroll
        for (int j = 0; j < 8; ++j) p[j] = (short)f2bf(st[(kq * 8 + j) * 260 + dcol]);
        *reinterpret_cast<short8*>(dst + kq * 8) = p;
    }
}

// ===================== main fused kernel: 512 thr, 32 q-rows/block, triangular skip ===========
__global__ __launch_bounds__(512, 4)
void attn_main(const float* __restrict__ Q, const unsigned short* __restrict__ KT,
               const unsigned short* __restrict__ VT, const int* __restrict__ RM,
               float* __restrict__ Out, float* __restrict__ Attn) {
    __shared__ short p_lds[32 * PSTR];   // 67072 B
    __shared__ float rm_f[1024];         // 4096 B

    const int tid  = threadIdx.x;
    const int lane = tid & 63;
    const int w    = tid >> 6;           // wave 0..7
    const int m    = lane & 15;
    const int quad = lane >> 4;
    const int wm   = w >> 2;             // m-tile 0..1
    const int wn   = w & 3;              // n-slice 0..3

    // XCD swizzle over 1024 blocks
    const int work = ((int)blockIdx.x & 7) * 128 + ((int)blockIdx.x >> 3);
    const int b  = work >> 5;
    const int qt = work & 31;            // q-tile of 32 rows
    const int colmax = (qt + 1) * 32;    // cols >= colmax are identically zero

    {
        const int2 mi = *reinterpret_cast<const int2*>(RM + b * S_ + tid * 2);
        rm_f[tid * 2]     = (float)mi.x;
        rm_f[tid * 2 + 1] = (float)mi.y;
    }

    // ---------------- Phase 1: raw scores = Q K^T (only active tiles) ----------------
    const int kw0 = wn * 256;
    const int tcnt = min(16, max(0, (colmax - kw0) >> 4));

    f32x4 acc1[16];
    #pragma unroll
    for (int t = 0; t < 16; ++t) acc1[t] = (f32x4){0.f, 0.f, 0.f, 0.f};

    const float* qbase = Q + ((size_t)(b * S_ + qt * 32 + wm * 16 + m)) * D_ + quad * 8;
    const unsigned short* kb = KT + (size_t)b * 524288 + (kw0 + m) * 32 + quad * 8;

    if (tcnt == 16) {
        for (int ds = 0; ds < 16; ++ds) {
            const float4 qa = *reinterpret_cast<const float4*>(qbase + ds * 32);
            const float4 qb = *reinterpret_cast<const float4*>(qbase + ds * 32 + 4);
            short8 af;
            af[0]=(short)f2bf(qa.x); af[1]=(short)f2bf(qa.y); af[2]=(short)f2bf(qa.z); af[3]=(short)f2bf(qa.w);
            af[4]=(short)f2bf(qb.x); af[5]=(short)f2bf(qb.y); af[6]=(short)f2bf(qb.z); af[7]=(short)f2bf(qb.w);
            const unsigned short* kds = kb + ds * 32768;
            #pragma unroll
            for (int t = 0; t < 16; ++t) {
                const short8 bf = *reinterpret_cast<const short8*>(kds + t * 512);
                acc1[t] = __builtin_amdgcn_mfma_f32_16x16x32_bf16(af, bf, acc1[t], 0, 0, 0);
            }
        }
    } else if (tcnt > 0) {
        for (int ds = 0; ds < 16; ++ds) {
            const float4 qa = *reinterpret_cast<const float4*>(qbase + ds * 32);
            const float4 qb = *reinterpret_cast<const float4*>(qbase + ds * 32 + 4);
            short8 af;
            af[0]=(short)f2bf(qa.x); af[1]=(short)f2bf(qa.y); af[2]=(short)f2bf(qa.z); af[3]=(short)f2bf(qa.w);
            af[4]=(short)f2bf(qb.x); af[5]=(short)f2bf(qb.y); af[6]=(short)f2bf(qb.z); af[7]=(short)f2bf(qb.w);
            const unsigned short* kds = kb + ds * 32768;
            for (int t = 0; t < tcnt; ++t) {
                const short8 bf = *reinterpret_cast<const short8*>(kds + t * 512);
                acc1[t] = __builtin_amdgcn_mfma_f32_16x16x32_bf16(af, bf, acc1[t], 0, 0, 0);
            }
        }
    }
    for (int t = 0; t < tcnt; ++t) {
        const int col = kw0 + t * 16 + m;
        #pragma unroll
        for (int r = 0; r < 4; ++r)
            p_lds[(wm * 16 + quad * 4 + r) * PSTR + col] = (short)f2bf(acc1[t][r]);
    }
    __syncthreads();

    // ---------------- softmax (reference-faithful masked variant) ----------------
    {
        const int r  = tid >> 4;          // 0..31
        const int kc = tid & 15;
        const int qg = qt * 32 + r;
        const float rmq = rm_f[qg];
        const float inv_scale = 0.04419417382415922f;   // 1/sqrt(512)
        const int jcnt = (colmax + 63) >> 6;            // active 64-col chunks

        float4 sv[16];
        float mx = 0.0f;
        for (int j = 0; j < jcnt; ++j) {
            const int k0 = 4 * kc + 64 * j;
            short4 s4 = *reinterpret_cast<const short4*>(&p_lds[r * PSTR + k0]);
            const float4 rmk = *reinterpret_cast<const float4*>(&rm_f[k0]);
            float s0 = bf2f((unsigned short)s4.x) * inv_scale;
            float s1 = bf2f((unsigned short)s4.y) * inv_scale;
            float s2 = bf2f((unsigned short)s4.z) * inv_scale;
            float s3 = bf2f((unsigned short)s4.w) * inv_scale;
            sv[j] = make_float4(s0, s1, s2, s3);
            if (rmq != 0.f) {
                if (rmk.x != 0.f && (k0+0) < qg) mx = fmaxf(mx, s0);
                if (rmk.y != 0.f && (k0+1) < qg) mx = fmaxf(mx, s1);
                if (rmk.z != 0.f && (k0+2) < qg) mx = fmaxf(mx, s2);
                if (rmk.w != 0.f && (k0+3) < qg) mx = fmaxf(mx, s3);
            }
        }
        #pragma unroll
        for (int off = 1; off < 16; off <<= 1) mx = fmaxf(mx, __shfl_xor(mx, off));

        float sum = 0.0f;
        for (int j = 0; j < jcnt; ++j) {
            const int k0 = 4 * kc + 64 * j;
            const float4 rmk = *reinterpret_cast<const float4*>(&rm_f[k0]);
            float p0 = 0.f, p1 = 0.f, p2 = 0.f, p3 = 0.f;
            if (rmq != 0.f) {
                if (rmk.x != 0.f && (k0+0) < qg) p0 = __expf(sv[j].x - mx);
                if (rmk.y != 0.f && (k0+1) < qg) p1 = __expf(sv[j].y - mx);
                if (rmk.z != 0.f && (k0+2) < qg) p2 = __expf(sv[j].z - mx);
                if (rmk.w != 0.f && (k0+3) < qg) p3 = __expf(sv[j].w - mx);
            }
            sv[j] = make_float4(p0, p1, p2, p3);
            sum += (p0 + p1) + (p2 + p3);
        }
        #pragma unroll
        for (int off = 1; off < 16; off <<= 1) sum += __shfl_xor(sum, off);

        float den = sum + ((sum == 0.0f) ? 1.0f : 0.0f);
        const float invd = 1.0f / (den + 1e-20f);

        float* arow = Attn + ((size_t)(b * S_) + qg) * S_;
        for (int j = 0; j < jcnt; ++j) {
            const int k0 = 4 * kc + 64 * j;
            float p0 = sv[j].x * invd, p1 = sv[j].y * invd;
            float p2 = sv[j].z * invd, p3 = sv[j].w * invd;
            *reinterpret_cast<float4*>(arow + k0) = make_float4(p0, p1, p2, p3);
            short4 pb;
            pb.x=(short)f2bf(p0); pb.y=(short)f2bf(p1); pb.z=(short)f2bf(p2); pb.w=(short)f2bf(p3);
            *reinterpret_cast<short4*>(&p_lds[r * PSTR + k0]) = pb;
        }
        const float4 zero4 = make_float4(0.f, 0.f, 0.f, 0.f);
        for (int j = jcnt; j < 16; ++j) {
            const int k0 = 4 * kc + 64 * j;
            *reinterpret_cast<float4*>(arow + k0) = zero4;   // masked region is exactly 0
        }
    }
    __syncthreads();

    // ---------------- Phase 2: Out = P V, contraction only over kk <= qt ----------------
    f32x4 acc2[8];
    #pragma unroll
    for (int i = 0; i < 8; ++i) acc2[i] = (f32x4){0.f, 0.f, 0.f, 0.f};

    const unsigned short* vb = VT + (size_t)b * 524288 + (wn * 8 * 16 + m) * 32 + quad * 8;
    const int kcnt = qt + 1;
    for (int kk = 0; kk < kcnt; ++kk) {
        const short8 af = *reinterpret_cast<const short8*>(
            &p_lds[(wm * 16 + m) * PSTR + kk * 32 + quad * 8]);
        const unsigned short* vkk = vb + kk * 16384;
        #pragma unroll
        for (int f = 0; f < 8; ++f) {
            const short8 bf = *reinterpret_cast<const short8*>(vkk + f * 512);
            acc2[f] = __builtin_amdgcn_mfma_f32_16x16x32_bf16(af, bf, acc2[f], 0, 0, 0);
        }
    }

    float* obase = Out + ((size_t)(b * S_ + qt * 32 + wm * 16)) * D_;
    #pragma unroll
    for (int f = 0; f < 8; ++f) {
        const int n0 = (wn * 8 + f) * 16 + m;
        #pragma unroll
        for (int r = 0; r < 4; ++r)
            obase[(size_t)(quad * 4 + r) * D_ + n0] = acc2[f][r];
    }
}

extern "C" void kernel_launch(void* const* d_in, const int* in_sizes, int n_in,
                              void* d_out, int out_size, void* d_ws, size_t ws_size,
                              hipStream_t stream) {
    (void)in_sizes; (void)n_in; (void)out_size;
    const float* q  = (const float*)d_in[0];
    const float* k  = (const float*)d_in[1];
    const float* v  = (const float*)d_in[2];
    const int*   rm = (const int*)d_in[3];
    float* out  = (float*)d_out;
    float* attn = out + (size_t)B_ * S_ * D_;

    unsigned short* KT = (unsigned short*)d_ws;
    unsigned short* VT = KT + (size_t)B_ * 524288;
    prep_k<<<dim3(B_ * 256), dim3(256), 0, stream>>>(k, KT);
    prep_v<<<dim3(B_ * 64), dim3(256), 0, stream>>>(v, VT);
    attn_main<<<dim3(B_ * (S_ / 32)), dim3(512), 0, stream>>>(q, KT, VT, rm, out, attn);
}